// Round 1
// baseline (625.484 us; speedup 1.0000x reference)
//
#include <hip/hip_runtime.h>
#include <math.h>

#define S 64
#define DIN 4
#define H 32
#define NHEADS 2
#define CF 16
#define DH 16
#define KSTRIDE 36   // floats per LDS row: 16B-aligned, breaks 32-bank power-of-2 stride

__global__ __launch_bounds__(64, 2)
void fused_fwd(const float* __restrict__ x,
               const float* __restrict__ c1w, const float* __restrict__ c1b,
               const float* __restrict__ c2w, const float* __restrict__ c2b,
               const float* __restrict__ cpw, const float* __restrict__ cpb,
               const float* __restrict__ ipw, const float* __restrict__ ipb,
               const float* __restrict__ wq, const float* __restrict__ bq,
               const float* __restrict__ wk, const float* __restrict__ bk,
               const float* __restrict__ wv, const float* __restrict__ bv,
               const float* __restrict__ wo, const float* __restrict__ bo,
               const float* __restrict__ lng, const float* __restrict__ lnb,
               const float* __restrict__ gw, const float* __restrict__ gb,
               const float* __restrict__ pw, const float* __restrict__ pb,
               const float* __restrict__ h1w, const float* __restrict__ h1b,
               const float* __restrict__ h2w, const float* __restrict__ h2b,
               float* __restrict__ out)
{
    __shared__ __attribute__((aligned(16))) float sm[2 * S * KSTRIDE]; // ks | vs ; ys reuses ks
    __shared__ float smc[192]; // combined[0..63] | gated[64..127] | fused[128..159] | t1[160..175]

    const int b = blockIdx.x;
    const int s = threadIdx.x;   // sequence position, one wave per block

    // ---- load x row (coalesced float4) ----
    const float4 xr = reinterpret_cast<const float4*>(x)[b * S + s];
    float x0[4] = {xr.x, xr.y, xr.z, xr.w};

    // ================= Conv branch (register + shuffle only) =================
    float xm[4], xp[4];
#pragma unroll
    for (int i = 0; i < 4; ++i) {
        float up = __shfl_up(x0[i], 1);
        float dn = __shfl_down(x0[i], 1);
        xm[i] = (s > 0) ? up : 0.f;
        xp[i] = (s < S - 1) ? dn : 0.f;
    }
    float hc[CF];
#pragma unroll
    for (int o = 0; o < CF; ++o) {
        float acc = c1b[o];
#pragma unroll
        for (int i = 0; i < DIN; ++i) {
            acc += xm[i] * c1w[(o * DIN + i) * 3 + 0];
            acc += x0[i] * c1w[(o * DIN + i) * 3 + 1];
            acc += xp[i] * c1w[(o * DIN + i) * 3 + 2];
        }
        hc[o] = fmaxf(acc, 0.f);
    }
    float hm[CF], hp[CF];
#pragma unroll
    for (int o = 0; o < CF; ++o) {
        float up = __shfl_up(hc[o], 1);
        float dn = __shfl_down(hc[o], 1);
        hm[o] = (s > 0) ? up : 0.f;
        hp[o] = (s < S - 1) ? dn : 0.f;
    }
    float h2r[CF];
#pragma unroll
    for (int o = 0; o < CF; ++o) {
        float acc = c2b[o];
#pragma unroll
        for (int i = 0; i < CF; ++i) {
            acc += hm[i] * c2w[(o * CF + i) * 3 + 0];
            acc += hc[i] * c2w[(o * CF + i) * 3 + 1];
            acc += hp[i] * c2w[(o * CF + i) * 3 + 2];
        }
        h2r[o] = fmaxf(acc, 0.f);
    }
    // AdaptiveAvgPool1d over s: full-wave butterfly (all lanes end with the sum)
#pragma unroll
    for (int o = 0; o < CF; ++o) {
        float v = h2r[o];
#pragma unroll
        for (int off = 32; off > 0; off >>= 1) v += __shfl_xor(v, off);
        h2r[o] = v * (1.f / 64.f);
    }
    if (s < H) {
        float acc = cpb[s];
#pragma unroll
        for (int o = 0; o < CF; ++o) acc += h2r[o] * cpw[s * CF + o];
        smc[s] = acc;   // conv_feat
    }

    // ================= Attention branch =================
    // h = x @ ipw.T + ipb   (per-lane row, weights are wave-uniform -> s_load)
    float hr[H];
#pragma unroll
    for (int j = 0; j < H; ++j) {
        hr[j] = ipb[j] + x0[0] * ipw[j * 4 + 0] + x0[1] * ipw[j * 4 + 1]
                       + x0[2] * ipw[j * 4 + 2] + x0[3] * ipw[j * 4 + 3];
    }

    float* ks = sm;
    float* vs = sm + S * KSTRIDE;
    // k, v rows -> LDS (vectorized 16B writes)
#pragma unroll
    for (int j4 = 0; j4 < H / 4; ++j4) {
        float4 kq, vq;
        float* kqf = reinterpret_cast<float*>(&kq);
        float* vqf = reinterpret_cast<float*>(&vq);
#pragma unroll
        for (int r = 0; r < 4; ++r) {
            const int j = j4 * 4 + r;
            float kk = bk[j], vv = bv[j];
#pragma unroll
            for (int c = 0; c < H; ++c) {
                kk += hr[c] * wk[j * H + c];
                vv += hr[c] * wv[j * H + c];
            }
            kqf[r] = kk;
            vqf[r] = vv;
        }
        reinterpret_cast<float4*>(&ks[s * KSTRIDE])[j4] = kq;
        reinterpret_cast<float4*>(&vs[s * KSTRIDE])[j4] = vq;
    }
    __syncthreads();

    float attn_out[H];
#pragma unroll
    for (int j = 0; j < H; ++j) attn_out[j] = bo[j];

#pragma unroll
    for (int head = 0; head < NHEADS; ++head) {
        // q row for this head (scale 1/sqrt(16) folded in)
        float qh[DH];
#pragma unroll
        for (int d = 0; d < DH; ++d) {
            const int j = head * DH + d;
            float acc = bq[j];
#pragma unroll
            for (int c = 0; c < H; ++c) acc += hr[c] * wq[j * H + c];
            qh[d] = acc * 0.25f;
        }
        // scores row (register array), stable softmax
        float sc[S];
        float mmax = -INFINITY;
#pragma unroll
        for (int kp = 0; kp < S; ++kp) {
            const float4* kr = reinterpret_cast<const float4*>(&ks[kp * KSTRIDE + head * DH]);
            float acc = 0.f;
#pragma unroll
            for (int dq = 0; dq < 4; ++dq) {
                float4 k4 = kr[dq];
                acc += qh[dq * 4 + 0] * k4.x + qh[dq * 4 + 1] * k4.y
                     + qh[dq * 4 + 2] * k4.z + qh[dq * 4 + 3] * k4.w;
            }
            sc[kp] = acc;
            mmax = fmaxf(mmax, acc);
        }
        float l = 0.f;
#pragma unroll
        for (int kp = 0; kp < S; ++kp) {
            float e = __expf(sc[kp] - mmax);
            sc[kp] = e;
            l += e;
        }
        const float inv = 1.f / l;
        float ctx[DH];
#pragma unroll
        for (int d = 0; d < DH; ++d) ctx[d] = 0.f;
#pragma unroll
        for (int kp = 0; kp < S; ++kp) {
            const float4* vr = reinterpret_cast<const float4*>(&vs[kp * KSTRIDE + head * DH]);
            const float p = sc[kp];
#pragma unroll
            for (int dq = 0; dq < 4; ++dq) {
                float4 v4 = vr[dq];
                ctx[dq * 4 + 0] += p * v4.x;
                ctx[dq * 4 + 1] += p * v4.y;
                ctx[dq * 4 + 2] += p * v4.z;
                ctx[dq * 4 + 3] += p * v4.w;
            }
        }
#pragma unroll
        for (int d = 0; d < DH; ++d) ctx[d] *= inv;
        // attn_out += ctx_head @ wo[:, head*16 : head*16+16].T
#pragma unroll
        for (int j = 0; j < H; ++j) {
            float acc = attn_out[j];
#pragma unroll
            for (int d = 0; d < DH; ++d) acc += ctx[d] * wo[j * H + head * DH + d];
            attn_out[j] = acc;
        }
    }

    // residual + LayerNorm over H
    float y[H];
    float mu = 0.f;
#pragma unroll
    for (int j = 0; j < H; ++j) { y[j] = hr[j] + attn_out[j]; mu += y[j]; }
    mu *= (1.f / 32.f);
    float var = 0.f;
#pragma unroll
    for (int j = 0; j < H; ++j) { float d = y[j] - mu; var += d * d; }
    var *= (1.f / 32.f);
    const float rstd = rsqrtf(var + 1e-5f);
#pragma unroll
    for (int j = 0; j < H; ++j) y[j] = (y[j] - mu) * rstd * lng[j] + lnb[j];

    // att_feat = mean over s: stage y to LDS (reuse ks region), column-sum
    __syncthreads();
    float* ys = sm;
#pragma unroll
    for (int j4 = 0; j4 < H / 4; ++j4) {
        float4 t;
        t.x = y[j4 * 4 + 0]; t.y = y[j4 * 4 + 1]; t.z = y[j4 * 4 + 2]; t.w = y[j4 * 4 + 3];
        reinterpret_cast<float4*>(&ys[s * KSTRIDE])[j4] = t;
    }
    __syncthreads();
    if (s < H) {
        float acc = 0.f;
#pragma unroll 8
        for (int t = 0; t < S; ++t) acc += ys[t * KSTRIDE + s];
        smc[H + s] = acc * (1.f / 64.f);   // att_feat
    }
    __syncthreads();

    // ================= DBMM fusion =================
    {
        const int j = s;   // all 64 lanes
        float acc = gb[j];
#pragma unroll 8
        for (int k2 = 0; k2 < 2 * H; ++k2) acc += smc[k2] * gw[j * 2 * H + k2];
        const float sig = 1.f / (1.f + __expf(-acc));
        smc[64 + j] = smc[j] * sig;        // gated
    }
    __syncthreads();
    if (s < H) {
        float acc = pb[s];
#pragma unroll 8
        for (int k2 = 0; k2 < 2 * H; ++k2) acc += smc[64 + k2] * pw[s * 2 * H + k2];
        smc[128 + s] = acc;                // fused
    }
    __syncthreads();

    // ================= Output head =================
    if (s < 16) {
        float acc = h1b[s];
#pragma unroll
        for (int c = 0; c < H; ++c) acc += smc[128 + c] * h1w[s * H + c];
        smc[160 + s] = fmaxf(acc, 0.f);    // t1
    }
    __syncthreads();
    if (s < 2) {
        float acc = h2b[s];
#pragma unroll
        for (int c = 0; c < 16; ++c) acc += smc[160 + c] * h2w[s * 16 + c];
        out[b * 2 + s] = acc;
    }
}

extern "C" void kernel_launch(void* const* d_in, const int* in_sizes, int n_in,
                              void* d_out, int out_size, void* d_ws, size_t ws_size,
                              hipStream_t stream) {
    (void)n_in; (void)d_ws; (void)ws_size;
    const int nb = out_size / 2;   // B
    const float* xp_   = (const float*)d_in[0];
    const float* c1w = (const float*)d_in[1];  const float* c1b = (const float*)d_in[2];
    const float* c2w = (const float*)d_in[3];  const float* c2b = (const float*)d_in[4];
    const float* cpw = (const float*)d_in[5];  const float* cpb = (const float*)d_in[6];
    const float* ipw = (const float*)d_in[7];  const float* ipb = (const float*)d_in[8];
    const float* wq  = (const float*)d_in[9];  const float* bq  = (const float*)d_in[10];
    const float* wk  = (const float*)d_in[11]; const float* bk  = (const float*)d_in[12];
    const float* wv  = (const float*)d_in[13]; const float* bv  = (const float*)d_in[14];
    const float* wo  = (const float*)d_in[15]; const float* bo  = (const float*)d_in[16];
    const float* lng = (const float*)d_in[17]; const float* lnb = (const float*)d_in[18];
    const float* gw  = (const float*)d_in[19]; const float* gb  = (const float*)d_in[20];
    const float* pw  = (const float*)d_in[21]; const float* pb  = (const float*)d_in[22];
    const float* h1w = (const float*)d_in[23]; const float* h1b = (const float*)d_in[24];
    const float* h2w = (const float*)d_in[25]; const float* h2b = (const float*)d_in[26];
    float* outp = (float*)d_out;

    dim3 grid(nb), block(64);
    hipLaunchKernelGGL(fused_fwd, grid, block, 0, stream,
                       xp_, c1w, c1b, c2w, c2b, cpw, cpb, ipw, ipb,
                       wq, bq, wk, bk, wv, bv, wo, bo, lng, lnb,
                       gw, gb, pw, pb, h1w, h1b, h2w, h2b, outp);
}